// Round 10
// baseline (283.694 us; speedup 1.0000x reference)
//
#include <hip/hip_runtime.h>
#include <hip/hip_bf16.h>

using bf16 = __hip_bfloat16;
typedef __bf16 bf16x8 __attribute__((ext_vector_type(8)));
typedef __bf16 bf16x4v __attribute__((ext_vector_type(4)));
typedef float f32x4 __attribute__((ext_vector_type(4)));

#define MFMA16(a, b, c) __builtin_amdgcn_mfma_f32_16x16x32_bf16((a), (b), (c), 0, 0, 0)

// N=65536, P=6, D=256, out=(N,27) fp32. Transposed MFMA scheme:
// A = weights (m = out-feature), B = points (n = point). 64 pts/block,
// 256 threads (4 waves); wave w owns features [64w,64w+64) in B/C, pts
// [16w,16w+16) in D.
// OCCUPANCY MODEL (r5-r9 measured): unified reg file = arch VGPR + AGPR acc,
// 512/wave-pair budget; 3 waves/SIMD needs <=168 total. This kernel: ~100
// arch + 64 acc = ~164 -> fits. LDS 37.9KB allows 4 blocks/CU; registers
// bind at 3 blocks/CU = 12 waves/CU (r5-r9 were all stuck at 8).
// __launch_bounds__(256,4) (r8) capped at 128 -> 200+MB scratch spill; (256,2)
// (r5) let the allocator bloat to 176 -> only 2/SIMD. (256,3) is the window.
// Feature order k': 0-7 frame, 8-10 tpts, 11-13 bigpts, 14-16 viewdir, 17-31 zero.
//
// ws (bf16): W1t [P][256 d1][32 k'] @0 (49152)
//            W2t [P][256 d2][256 d1] @49152 (393216)
//            W3t [P][32 r][256 d2] @442368 (49152)  r<20:W3, r==20:Wocc, else 0

__global__ void prep_kernel(const float* __restrict__ W1, const float* __restrict__ W2,
                            const float* __restrict__ W3, const float* __restrict__ Wocc,
                            __bf16* __restrict__ ws) {
  const int t = blockIdx.x * 256 + threadIdx.x;
  if (t < 49152) {  // W2t: one 8-wide k-chunk per thread, lanes n-major => coalesced
    const int p = t >> 13, r = t & 8191, n = r >> 5, c = r & 31;
    const float* src = W2 + p * 65536 + c * 8 * 256 + n;
    bf16x8 v;
#pragma unroll
    for (int j = 0; j < 8; ++j) v[j] = (__bf16)src[j * 256];
    *reinterpret_cast<bf16x8*>(&ws[49152 + p * 65536 + n * 256 + c * 8]) = v;
  } else if (t < 55296) {  // W1t (reordered features)
    const int u = t - 49152;
    const int p = u >> 10, r = u & 1023, n = r >> 2, c = r & 3;
    bf16x8 v;
#pragma unroll
    for (int j = 0; j < 8; ++j) {
      const int k = c * 8 + j;
      float x = 0.f;
      if (k < 17) {
        const int ko = (k < 8) ? k + 3 : ((k < 11) ? k - 8 : k);
        x = W1[p * 4352 + ko * 256 + n];
      }
      v[j] = (__bf16)x;
    }
    *reinterpret_cast<bf16x8*>(&ws[p * 8192 + n * 32 + c * 8]) = v;
  } else if (t < 61440) {  // W3t (W3 || Wocc || zeros)
    const int u = t - 55296;
    const int p = u >> 10, r = u & 1023, row = r >> 5, c = r & 31;
    bf16x8 v;
#pragma unroll
    for (int j = 0; j < 8; ++j) {
      const int k = c * 8 + j;
      float x = 0.f;
      if (row < 20)       x = W3[p * 5120 + k * 20 + row];
      else if (row == 20) x = Wocc[p * 256 + k];
      v[j] = (__bf16)x;
    }
    *reinterpret_cast<bf16x8*>(&ws[442368 + p * 8192 + row * 256 + c * 8]) = v;
  }
}

// Hf [pt][256 d] (32 16B-chunks/row), XOR swizzle chunk^=(pt&7): b64 writes
// 4 accesses/bank, b128 reads 8/bank (both at throughput minimum).
__global__ __launch_bounds__(256, 3) void tpose_main(
    const float* __restrict__ tpts, const float* __restrict__ bigpts,
    const float* __restrict__ viewdir, const float* __restrict__ frame,
    const float* __restrict__ b1g, const float* __restrict__ b2g,
    const float* __restrict__ b3g, const float* __restrict__ boccg,
    const int* __restrict__ tflag, const __bf16* __restrict__ ws,
    float* __restrict__ out) {
  const __bf16* __restrict__ W1t = ws;
  const __bf16* __restrict__ W2t = ws + 49152;
  const __bf16* __restrict__ W3t = ws + 442368;

  __shared__ __align__(16) __bf16 Xf[64 * 40];    // [pt][k' pad 40]  5 KB
  __shared__ __align__(16) __bf16 Hf[64 * 256];   // swizzled         32 KB

  const int tid = threadIdx.x;
  const int w = tid >> 6;
  const int lane = tid & 63;
  const int lq = lane >> 4;
  const int ln = lane & 15;
  const int e = ln & 7;           // swizzle key (row & 7 == ln & 7 at every use)
  const int n0 = blockIdx.x * 64;

  // one-time X init: frame octet + zero tail (visible via barrier (1))
  if (tid < 64) {
    bf16x8 f8;
#pragma unroll
    for (int j = 0; j < 8; ++j) f8[j] = (__bf16)frame[j];
    *reinterpret_cast<bf16x8*>(&Xf[tid * 40]) = f8;
    bf16x8 z = {};
    *reinterpret_cast<bf16x8*>(&Xf[tid * 40 + 16]) = z;
    *reinterpret_cast<bf16x8*>(&Xf[tid * 40 + 24]) = z;
  }

  float psum0[4] = {0.f, 0.f, 0.f, 0.f};  // raw dims lq*4+r (0..15)
  float psum1[4] = {0.f, 0.f, 0.f, 0.f};  // dims 16..20 (lq0: 16-19, lq1 r0: 20)

  for (int p = 0; p < 6; ++p) {
    // flag prefetch (consumed only at epilogue -> latency hidden by B/C/D)
    const float fl = (tflag[(n0 + w * 16 + ln) * 6 + p] != 0) ? 1.f : 0.f;

    // ---- Phase A: dynamic features, 4 lanes per pt (3 roles live) ----
    {
      const int pt = tid >> 2, role = tid & 3;
      const int base3 = ((n0 + pt) * 6 + p) * 3;
      if (role == 0) {
#pragma unroll
        for (int i = 0; i < 3; ++i) Xf[pt * 40 + 8 + i] = (__bf16)tpts[base3 + i];
      } else if (role == 1) {
#pragma unroll
        for (int i = 0; i < 3; ++i) Xf[pt * 40 + 11 + i] = (__bf16)bigpts[base3 + i];
      } else if (role == 2) {
#pragma unroll
        for (int i = 0; i < 3; ++i) Xf[pt * 40 + 14 + i] = (__bf16)viewdir[base3 + i];
      }
    }

    __syncthreads();  // (1) X visible; prev part's phase-D Hf reads done

    // ---- Phase B: H1 = relu(W1^T X + b1); wave w -> d1 [64w, 64w+64) ----
    f32x4 acc[4][4];
#pragma unroll
    for (int mt = 0; mt < 4; ++mt)
#pragma unroll
      for (int nt = 0; nt < 4; ++nt) acc[mt][nt] = f32x4{0.f, 0.f, 0.f, 0.f};
    {
      bf16x8 aw[4];
#pragma unroll
      for (int mt = 0; mt < 4; ++mt)
        aw[mt] = *reinterpret_cast<const bf16x8*>(
            &W1t[p * 8192 + (w * 64 + mt * 16 + ln) * 32 + lq * 8]);
#pragma unroll
      for (int nt = 0; nt < 4; ++nt) {
        const bf16x8 xb =
            *reinterpret_cast<const bf16x8*>(&Xf[(nt * 16 + ln) * 40 + lq * 8]);
#pragma unroll
        for (int mt = 0; mt < 4; ++mt) acc[mt][nt] = MFMA16(aw[mt], xb, acc[mt][nt]);
      }
    }
    {  // writeback (+b1, relu); bias loaded here to keep live range short
      f32x4 b1v[4];
#pragma unroll
      for (int mt = 0; mt < 4; ++mt)
        b1v[mt] = *reinterpret_cast<const f32x4*>(
            &b1g[p * 256 + w * 64 + mt * 16 + lq * 4]);
#pragma unroll
      for (int mt = 0; mt < 4; ++mt) {
        const int c = w * 8 + mt * 2 + (lq >> 1);
        const int off = ((c ^ e) << 3) + (lq & 1) * 4;
#pragma unroll
        for (int nt = 0; nt < 4; ++nt) {
          bf16x4v hv;
#pragma unroll
          for (int r = 0; r < 4; ++r)
            hv[r] = (__bf16)fmaxf(acc[mt][nt][r] + b1v[mt][r], 0.f);
          *reinterpret_cast<bf16x4v*>(&Hf[(nt * 16 + ln) * 256 + off]) = hv;
        }
      }
    }

    __syncthreads();  // (2) H1 visible

    // ---- Phase C: H2 = relu(W2^T H1 + b2) ----
#pragma unroll
    for (int mt = 0; mt < 4; ++mt)
#pragma unroll
      for (int nt = 0; nt < 4; ++nt) acc[mt][nt] = f32x4{0.f, 0.f, 0.f, 0.f};
    const __bf16* __restrict__ w2p = W2t + p * 65536 + (w * 64 + ln) * 256 + lq * 8;
#pragma unroll
    for (int kk = 0; kk < 8; ++kk) {
      bf16x8 a2[4];
#pragma unroll
      for (int mt = 0; mt < 4; ++mt)
        a2[mt] = *reinterpret_cast<const bf16x8*>(w2p + mt * 4096 + kk * 32);
#pragma unroll
      for (int nt = 0; nt < 4; ++nt) {
        const bf16x8 hb = *reinterpret_cast<const bf16x8*>(
            &Hf[(nt * 16 + ln) * 256 + (((kk * 4 + lq) ^ e) << 3)]);
#pragma unroll
        for (int mt = 0; mt < 4; ++mt) acc[mt][nt] = MFMA16(a2[mt], hb, acc[mt][nt]);
      }
    }

    __syncthreads();  // (3) H1 reads done before overwrite

    {
      f32x4 b2v[4];
#pragma unroll
      for (int mt = 0; mt < 4; ++mt)
        b2v[mt] = *reinterpret_cast<const f32x4*>(
            &b2g[p * 256 + w * 64 + mt * 16 + lq * 4]);
#pragma unroll
      for (int mt = 0; mt < 4; ++mt) {
        const int c = w * 8 + mt * 2 + (lq >> 1);
        const int off = ((c ^ e) << 3) + (lq & 1) * 4;
#pragma unroll
        for (int nt = 0; nt < 4; ++nt) {
          bf16x4v hv;
#pragma unroll
          for (int r = 0; r < 4; ++r)
            hv[r] = (__bf16)fmaxf(acc[mt][nt][r] + b2v[mt][r], 0.f);
          *reinterpret_cast<bf16x4v*>(&Hf[(nt * 16 + ln) * 256 + off]) = hv;
        }
      }
    }

    __syncthreads();  // (4) H2 visible

    // ---- Phase D: raw||occ = W3^T H2; wave w -> pts [16w, 16w+16) ----
    f32x4 acc3[2];
    acc3[0] = f32x4{0.f, 0.f, 0.f, 0.f};
    acc3[1] = f32x4{0.f, 0.f, 0.f, 0.f};
    const __bf16* __restrict__ w3p = W3t + p * 8192 + ln * 256 + lq * 8;
#pragma unroll
    for (int kk = 0; kk < 8; ++kk) {
      const bf16x8 hb = *reinterpret_cast<const bf16x8*>(
          &Hf[(w * 16 + ln) * 256 + (((kk * 4 + lq) ^ e) << 3)]);
#pragma unroll
      for (int mt = 0; mt < 2; ++mt) {
        const bf16x8 a3 =
            *reinterpret_cast<const bf16x8*>(w3p + mt * 4096 + kk * 32);
        acc3[mt] = MFMA16(a3, hb, acc3[mt]);
      }
    }

    // Epilogue
    {
      float b3v[2][4];
#pragma unroll
      for (int mt = 0; mt < 2; ++mt)
#pragma unroll
        for (int r = 0; r < 4; ++r) {
          const int d = mt * 16 + lq * 4 + r;
          float v = 0.f;
          if (d < 20)       v = b3g[p * 20 + d];
          else if (d == 20) v = boccg[p];
          b3v[mt][r] = v;
        }
      const int pt = n0 + w * 16 + ln;
#pragma unroll
      for (int r = 0; r < 4; ++r) psum0[r] += fl * (acc3[0][r] + b3v[0][r]);
      if (lq == 0) {
#pragma unroll
        for (int r = 0; r < 4; ++r) psum1[r] += fl * (acc3[1][r] + b3v[1][r]);
      } else if (lq == 1) {  // dim 20 = occ (r=0)
        const float occ = 1.f / (1.f + __expf(-(acc3[1][0] + b3v[1][0])));
        out[pt * 27 + 21 + p] = fl * occ;
        psum1[0] += fl * occ;
      }
    }
  }  // p loop

  const float inv6 = 1.f / 6.f;
  const int pt = n0 + w * 16 + ln;
#pragma unroll
  for (int r = 0; r < 4; ++r) out[pt * 27 + lq * 4 + r] = psum0[r] * inv6;
  if (lq == 0) {
#pragma unroll
    for (int r = 0; r < 4; ++r) out[pt * 27 + 16 + r] = psum1[r] * inv6;
  } else if (lq == 1) {
    out[pt * 27 + 20] = psum1[0] * inv6;
  }
}

extern "C" void kernel_launch(void* const* d_in, const int* in_sizes, int n_in,
                              void* d_out, int out_size, void* d_ws, size_t ws_size,
                              hipStream_t stream) {
  const float* tpts    = (const float*)d_in[0];
  const float* bigpts  = (const float*)d_in[1];
  const float* viewdir = (const float*)d_in[2];
  const float* frame   = (const float*)d_in[5];
  const float* W1      = (const float*)d_in[6];
  const float* b1      = (const float*)d_in[7];
  const float* W2      = (const float*)d_in[8];
  const float* b2      = (const float*)d_in[9];
  const float* W3      = (const float*)d_in[10];
  const float* b3      = (const float*)d_in[11];
  const float* Wocc    = (const float*)d_in[12];
  const float* bocc    = (const float*)d_in[13];
  const int*   tflag   = (const int*)d_in[14];
  __bf16* ws  = (__bf16*)d_ws;
  float*  out = (float*)d_out;

  prep_kernel<<<240, 256, 0, stream>>>(W1, W2, W3, Wocc, ws);
  tpose_main<<<1024, 256, 0, stream>>>(tpts, bigpts, viewdir, frame, b1, b2, b3,
                                       bocc, tflag, ws, out);
}

// Round 11
// 203.492 us; speedup vs baseline: 1.3941x; 1.3941x over previous
//
#include <hip/hip_runtime.h>
#include <hip/hip_bf16.h>

using bf16 = __hip_bfloat16;
typedef __bf16 bf16x8 __attribute__((ext_vector_type(8)));
typedef __bf16 bf16x4v __attribute__((ext_vector_type(4)));
typedef float f32x4 __attribute__((ext_vector_type(4)));

#define MFMA16(a, b, c) __builtin_amdgcn_mfma_f32_16x16x32_bf16((a), (b), (c), 0, 0, 0)

// N=65536, P=6, D=256, out=(N,27) fp32. Transposed MFMA scheme:
// A = weights (m = out-feature), B = points (n = point). 128 pts/block,
// 256 threads (4 waves): wave w owns features [64w,64w+64) in B/C, pts
// [32w,32w+32) in D.
// OCCUPANCY MODEL (r3-r10 measured): HW rounds unified (VGPR+AGPR) alloc to
// a power of two; waves/SIMD steps only at 64/128/256 total. This kernel:
// ~118 arch + 128 acc = ~246 -> 2 waves/SIMD (8 waves/CU). Going above 8
// waves needs total<=128 which costs ~50 regs of spill (r8: 200+MB scratch).
// So: stay at 2/SIMD, maximize per-barrier-interval work (128 pts), zero spill.
// Bias-1 trick: X feature k'=17 == 1.0, W1t k=17 column == b1 -> layer-1 bias
// comes out of the MFMA, no bias registers or adds.
// Feature order k': 0-7 frame, 8-10 tpts, 11-13 bigpts, 14-16 viewdir,
//                   17 = 1.0, 18-31 zero.
//
// ws (bf16): W1t [P][256 d1][32 k'] @0 (49152)
//            W2t [P][256 d2][256 d1] @49152 (393216)
//            W3t [P][32 r][256 d2] @442368 (49152)  r<20:W3, r==20:Wocc, else 0

__global__ void prep_kernel(const float* __restrict__ W1, const float* __restrict__ b1,
                            const float* __restrict__ W2, const float* __restrict__ W3,
                            const float* __restrict__ Wocc, __bf16* __restrict__ ws) {
  const int t = blockIdx.x * 256 + threadIdx.x;
  if (t < 49152) {  // W2t: one 8-wide k-chunk per thread, lanes n-major => coalesced
    const int p = t >> 13, r = t & 8191, n = r >> 5, c = r & 31;
    const float* src = W2 + p * 65536 + c * 8 * 256 + n;
    bf16x8 v;
#pragma unroll
    for (int j = 0; j < 8; ++j) v[j] = (__bf16)src[j * 256];
    *reinterpret_cast<bf16x8*>(&ws[49152 + p * 65536 + n * 256 + c * 8]) = v;
  } else if (t < 55296) {  // W1t (reordered features, b1 at k=17)
    const int u = t - 49152;
    const int p = u >> 10, r = u & 1023, n = r >> 2, c = r & 3;
    bf16x8 v;
#pragma unroll
    for (int j = 0; j < 8; ++j) {
      const int k = c * 8 + j;
      float x = 0.f;
      if (k < 17) {
        const int ko = (k < 8) ? k + 3 : ((k < 11) ? k - 8 : k);
        x = W1[p * 4352 + ko * 256 + n];
      } else if (k == 17) {
        x = b1[p * 256 + n];
      }
      v[j] = (__bf16)x;
    }
    *reinterpret_cast<bf16x8*>(&ws[p * 8192 + n * 32 + c * 8]) = v;
  } else if (t < 61440) {  // W3t (W3 || Wocc || zeros)
    const int u = t - 55296;
    const int p = u >> 10, r = u & 1023, row = r >> 5, c = r & 31;
    bf16x8 v;
#pragma unroll
    for (int j = 0; j < 8; ++j) {
      const int k = c * 8 + j;
      float x = 0.f;
      if (row < 20)       x = W3[p * 5120 + k * 20 + row];
      else if (row == 20) x = Wocc[p * 256 + k];
      v[j] = (__bf16)x;
    }
    *reinterpret_cast<bf16x8*>(&ws[442368 + p * 8192 + row * 256 + c * 8]) = v;
  }
}

// Hf [pt][256 d] (32 16B-chunks/row), XOR swizzle chunk^=(pt&7): b64 writes
// 4 accesses/bank, b128 reads 8/bank (both at throughput minimum).
__global__ __launch_bounds__(256, 2) void tpose_main(
    const float* __restrict__ tpts, const float* __restrict__ bigpts,
    const float* __restrict__ viewdir, const float* __restrict__ frame,
    const float* __restrict__ b2g, const float* __restrict__ b3g,
    const float* __restrict__ boccg, const int* __restrict__ tflag,
    const __bf16* __restrict__ ws, float* __restrict__ out) {
  const __bf16* __restrict__ W1t = ws;
  const __bf16* __restrict__ W2t = ws + 49152;
  const __bf16* __restrict__ W3t = ws + 442368;

  __shared__ __align__(16) __bf16 Xf[128 * 40];    // [pt][k' pad 40]  10 KB
  __shared__ __align__(16) __bf16 Hf[128 * 256];   // swizzled         64 KB

  const int tid = threadIdx.x;
  const int w = tid >> 6;
  const int lane = tid & 63;
  const int lq = lane >> 4;
  const int ln = lane & 15;
  const int e = ln & 7;           // swizzle key (row & 7 == ln & 7 at every use)
  const int n0 = blockIdx.x * 128;

  // one-time X init: frame octet, 1.0 at slot 17, zeros 18-31
  if (tid < 128) {
    bf16x8 f8;
#pragma unroll
    for (int j = 0; j < 8; ++j) f8[j] = (__bf16)frame[j];
    *reinterpret_cast<bf16x8*>(&Xf[tid * 40]) = f8;
    bf16x8 z = {};
    z[1] = (__bf16)1.0f;  // slot 17 = constant-1 (bias feature)
    *reinterpret_cast<bf16x8*>(&Xf[tid * 40 + 16]) = z;
    bf16x8 z2 = {};
    *reinterpret_cast<bf16x8*>(&Xf[tid * 40 + 24]) = z2;
  }

  const int role = tid & 3;  // 0: tpts, 1: bigpts, 2: viewdir, 3: idle
  const float* __restrict__ dynsrc =
      (role == 0) ? tpts : (role == 1) ? bigpts : viewdir;

  // prefetch state for part 0
  float pre[2][3];
  float flv[2];
#pragma unroll
  for (int pass = 0; pass < 2; ++pass) {
    const int pt = (tid >> 2) + pass * 64;
    const int base3 = (n0 + pt) * 18;  // p=0
#pragma unroll
    for (int i = 0; i < 3; ++i) pre[pass][i] = dynsrc[base3 + i];
  }
#pragma unroll
  for (int s = 0; s < 2; ++s)
    flv[s] = (tflag[(n0 + w * 32 + s * 16 + ln) * 6] != 0) ? 1.f : 0.f;

  float psum0[2][4] = {{0.f, 0.f, 0.f, 0.f}, {0.f, 0.f, 0.f, 0.f}};
  float psum1[2][4] = {{0.f, 0.f, 0.f, 0.f}, {0.f, 0.f, 0.f, 0.f}};

  for (int p = 0; p < 6; ++p) {
    // ---- Phase A: store prefetched features (pure LDS) ----
    if (role < 3) {
#pragma unroll
      for (int pass = 0; pass < 2; ++pass) {
        const int pt = (tid >> 2) + pass * 64;
#pragma unroll
        for (int i = 0; i < 3; ++i)
          Xf[pt * 40 + 8 + role * 3 + i] = (__bf16)pre[pass][i];
      }
    }

    // prefetch part p+1 (latency hidden behind phases B-D)
    const int pn = (p < 5) ? p + 1 : 5;
    float fln[2];
#pragma unroll
    for (int pass = 0; pass < 2; ++pass) {
      const int pt = (tid >> 2) + pass * 64;
      const int base3 = ((n0 + pt) * 6 + pn) * 3;
#pragma unroll
      for (int i = 0; i < 3; ++i) pre[pass][i] = dynsrc[base3 + i];
    }
#pragma unroll
    for (int s = 0; s < 2; ++s)
      fln[s] = (tflag[(n0 + w * 32 + s * 16 + ln) * 6 + pn] != 0) ? 1.f : 0.f;

    __syncthreads();  // (1) X visible; prev part's phase-D Hf reads done

    // ---- Phase B: H1 = relu(W1^T X) (bias inside GEMM via slot 17) ----
    f32x4 acc[4][8];
#pragma unroll
    for (int mt = 0; mt < 4; ++mt)
#pragma unroll
      for (int nt = 0; nt < 8; ++nt) acc[mt][nt] = f32x4{0.f, 0.f, 0.f, 0.f};
    {
      bf16x8 aw[4];
#pragma unroll
      for (int mt = 0; mt < 4; ++mt)
        aw[mt] = *reinterpret_cast<const bf16x8*>(
            &W1t[p * 8192 + (w * 64 + mt * 16 + ln) * 32 + lq * 8]);
#pragma unroll
      for (int nt = 0; nt < 8; ++nt) {
        const bf16x8 xb =
            *reinterpret_cast<const bf16x8*>(&Xf[(nt * 16 + ln) * 40 + lq * 8]);
#pragma unroll
        for (int mt = 0; mt < 4; ++mt) acc[mt][nt] = MFMA16(aw[mt], xb, acc[mt][nt]);
      }
    }
#pragma unroll
    for (int mt = 0; mt < 4; ++mt) {
      const int c = w * 8 + mt * 2 + (lq >> 1);
      const int off = ((c ^ e) << 3) + (lq & 1) * 4;
#pragma unroll
      for (int nt = 0; nt < 8; ++nt) {
        bf16x4v hv;
#pragma unroll
        for (int r = 0; r < 4; ++r) hv[r] = (__bf16)fmaxf(acc[mt][nt][r], 0.f);
        *reinterpret_cast<bf16x4v*>(&Hf[(nt * 16 + ln) * 256 + off]) = hv;
      }
    }

    __syncthreads();  // (2) H1 visible

    // ---- Phase C: H2 = relu(W2^T H1 + b2) ----
#pragma unroll
    for (int mt = 0; mt < 4; ++mt)
#pragma unroll
      for (int nt = 0; nt < 8; ++nt) acc[mt][nt] = f32x4{0.f, 0.f, 0.f, 0.f};
    const __bf16* __restrict__ w2p = W2t + p * 65536 + (w * 64 + ln) * 256 + lq * 8;
#pragma unroll
    for (int kk = 0; kk < 8; ++kk) {
      bf16x8 a2[4];
#pragma unroll
      for (int mt = 0; mt < 4; ++mt)
        a2[mt] = *reinterpret_cast<const bf16x8*>(w2p + mt * 4096 + kk * 32);
#pragma unroll
      for (int nt = 0; nt < 8; ++nt) {
        const bf16x8 hb = *reinterpret_cast<const bf16x8*>(
            &Hf[(nt * 16 + ln) * 256 + (((kk * 4 + lq) ^ e) << 3)]);
#pragma unroll
        for (int mt = 0; mt < 4; ++mt) acc[mt][nt] = MFMA16(a2[mt], hb, acc[mt][nt]);
      }
    }

    __syncthreads();  // (3) H1 reads done before overwrite

    {
      f32x4 b2v[4];
#pragma unroll
      for (int mt = 0; mt < 4; ++mt)
        b2v[mt] = *reinterpret_cast<const f32x4*>(
            &b2g[p * 256 + w * 64 + mt * 16 + lq * 4]);
#pragma unroll
      for (int mt = 0; mt < 4; ++mt) {
        const int c = w * 8 + mt * 2 + (lq >> 1);
        const int off = ((c ^ e) << 3) + (lq & 1) * 4;
#pragma unroll
        for (int nt = 0; nt < 8; ++nt) {
          bf16x4v hv;
#pragma unroll
          for (int r = 0; r < 4; ++r)
            hv[r] = (__bf16)fmaxf(acc[mt][nt][r] + b2v[mt][r], 0.f);
          *reinterpret_cast<bf16x4v*>(&Hf[(nt * 16 + ln) * 256 + off]) = hv;
        }
      }
    }

    __syncthreads();  // (4) H2 visible

    // ---- Phase D: raw||occ = W3^T H2; wave w -> pts [32w, 32w+32) ----
    f32x4 acc3[2][2];
#pragma unroll
    for (int mt = 0; mt < 2; ++mt)
#pragma unroll
      for (int s = 0; s < 2; ++s) acc3[mt][s] = f32x4{0.f, 0.f, 0.f, 0.f};
    const __bf16* __restrict__ w3p = W3t + p * 8192 + ln * 256 + lq * 8;
#pragma unroll
    for (int kk = 0; kk < 8; ++kk) {
      bf16x8 a3[2];
#pragma unroll
      for (int mt = 0; mt < 2; ++mt)
        a3[mt] = *reinterpret_cast<const bf16x8*>(w3p + mt * 4096 + kk * 32);
#pragma unroll
      for (int s = 0; s < 2; ++s) {
        const bf16x8 hb = *reinterpret_cast<const bf16x8*>(
            &Hf[(w * 32 + s * 16 + ln) * 256 + (((kk * 4 + lq) ^ e) << 3)]);
#pragma unroll
        for (int mt = 0; mt < 2; ++mt) acc3[mt][s] = MFMA16(a3[mt], hb, acc3[mt][s]);
      }
    }

    // Epilogue
    {
      float b3v[2][4];
#pragma unroll
      for (int mt = 0; mt < 2; ++mt)
#pragma unroll
        for (int r = 0; r < 4; ++r) {
          const int d = mt * 16 + lq * 4 + r;
          float v = 0.f;
          if (d < 20)       v = b3g[p * 20 + d];
          else if (d == 20) v = boccg[p];
          b3v[mt][r] = v;
        }
#pragma unroll
      for (int s = 0; s < 2; ++s) {
        const int pt = n0 + w * 32 + s * 16 + ln;
#pragma unroll
        for (int r = 0; r < 4; ++r) psum0[s][r] += flv[s] * (acc3[0][s][r] + b3v[0][r]);
        if (lq == 0) {
#pragma unroll
          for (int r = 0; r < 4; ++r) psum1[s][r] += flv[s] * (acc3[1][s][r] + b3v[1][r]);
        } else if (lq == 1) {  // dim 20 = occ (r=0)
          const float occ = 1.f / (1.f + __expf(-(acc3[1][s][0] + b3v[1][0])));
          out[pt * 27 + 21 + p] = flv[s] * occ;
          psum1[s][0] += flv[s] * occ;
        }
      }
    }

    flv[0] = fln[0];
    flv[1] = fln[1];
  }  // p loop

  const float inv6 = 1.f / 6.f;
#pragma unroll
  for (int s = 0; s < 2; ++s) {
    const int pt = n0 + w * 32 + s * 16 + ln;
#pragma unroll
    for (int r = 0; r < 4; ++r) out[pt * 27 + lq * 4 + r] = psum0[s][r] * inv6;
    if (lq == 0) {
#pragma unroll
      for (int r = 0; r < 4; ++r) out[pt * 27 + 16 + r] = psum1[s][r] * inv6;
    } else if (lq == 1) {
      out[pt * 27 + 20] = psum1[s][0] * inv6;
    }
  }
}

extern "C" void kernel_launch(void* const* d_in, const int* in_sizes, int n_in,
                              void* d_out, int out_size, void* d_ws, size_t ws_size,
                              hipStream_t stream) {
  const float* tpts    = (const float*)d_in[0];
  const float* bigpts  = (const float*)d_in[1];
  const float* viewdir = (const float*)d_in[2];
  const float* frame   = (const float*)d_in[5];
  const float* W1      = (const float*)d_in[6];
  const float* b1      = (const float*)d_in[7];
  const float* W2      = (const float*)d_in[8];
  const float* b2      = (const float*)d_in[9];
  const float* W3      = (const float*)d_in[10];
  const float* b3      = (const float*)d_in[11];
  const float* Wocc    = (const float*)d_in[12];
  const float* bocc    = (const float*)d_in[13];
  const int*   tflag   = (const int*)d_in[14];
  __bf16* ws  = (__bf16*)d_ws;
  float*  out = (float*)d_out;

  prep_kernel<<<240, 256, 0, stream>>>(W1, b1, W2, W3, Wocc, ws);
  tpose_main<<<512, 256, 0, stream>>>(tpts, bigpts, viewdir, frame, b2, b3,
                                      bocc, tflag, ws, out);
}

// Round 12
// 198.671 us; speedup vs baseline: 1.4280x; 1.0243x over previous
//
#include <hip/hip_runtime.h>
#include <hip/hip_bf16.h>

using bf16 = __hip_bfloat16;
typedef __bf16 bf16x8 __attribute__((ext_vector_type(8)));
typedef __bf16 bf16x4v __attribute__((ext_vector_type(4)));
typedef float f32x4 __attribute__((ext_vector_type(4)));

#define MFMA16(a, b, c) __builtin_amdgcn_mfma_f32_16x16x32_bf16((a), (b), (c), 0, 0, 0)

// N=65536, P=6, D=256, out=(N,27) fp32. Transposed MFMA scheme:
// A = weights (m = out-feature), B = points (n = point). 128 pts/block,
// 256 threads (4 waves): wave w owns features [64w,64w+64) in B/C, pts
// [32w,32w+32) in D.
// OCCUPANCY MODEL (r3-r10): unified (VGPR+AGPR) alloc rounds to power of two;
// waves/SIMD step at 64/128/256 total. Operating point: 2/SIMD (8 waves/CU),
// maximize per-barrier work (128 pts), minimize pressure at phase-C peak.
// Bias handling: b1 inside layer-1 GEMM (X slot 17 = 1.0, W1t k=17 = b1);
// b2/b3 preloaded into MFMA accumulators (C-operand is additive) -> writebacks
// are relu-only and bias regs die before the k-loops.
// Feature order k': 0-7 frame, 8-10 tpts, 11-13 bigpts, 14-16 viewdir,
//                   17 = 1.0, 18-31 zero.
//
// ws (bf16): W1t [P][256 d1][32 k'] @0 (49152)
//            W2t [P][256 d2][256 d1] @49152 (393216)
//            W3t [P][32 r][256 d2] @442368 (49152)  r<20:W3, r==20:Wocc, else 0

__global__ void prep_kernel(const float* __restrict__ W1, const float* __restrict__ b1,
                            const float* __restrict__ W2, const float* __restrict__ W3,
                            const float* __restrict__ Wocc, __bf16* __restrict__ ws) {
  const int t = blockIdx.x * 256 + threadIdx.x;
  if (t < 49152) {  // W2t: one 8-wide k-chunk per thread, lanes n-major => coalesced
    const int p = t >> 13, r = t & 8191, n = r >> 5, c = r & 31;
    const float* src = W2 + p * 65536 + c * 8 * 256 + n;
    bf16x8 v;
#pragma unroll
    for (int j = 0; j < 8; ++j) v[j] = (__bf16)src[j * 256];
    *reinterpret_cast<bf16x8*>(&ws[49152 + p * 65536 + n * 256 + c * 8]) = v;
  } else if (t < 55296) {  // W1t (reordered features, b1 at k=17)
    const int u = t - 49152;
    const int p = u >> 10, r = u & 1023, n = r >> 2, c = r & 3;
    bf16x8 v;
#pragma unroll
    for (int j = 0; j < 8; ++j) {
      const int k = c * 8 + j;
      float x = 0.f;
      if (k < 17) {
        const int ko = (k < 8) ? k + 3 : ((k < 11) ? k - 8 : k);
        x = W1[p * 4352 + ko * 256 + n];
      } else if (k == 17) {
        x = b1[p * 256 + n];
      }
      v[j] = (__bf16)x;
    }
    *reinterpret_cast<bf16x8*>(&ws[p * 8192 + n * 32 + c * 8]) = v;
  } else if (t < 61440) {  // W3t (W3 || Wocc || zeros)
    const int u = t - 55296;
    const int p = u >> 10, r = u & 1023, row = r >> 5, c = r & 31;
    bf16x8 v;
#pragma unroll
    for (int j = 0; j < 8; ++j) {
      const int k = c * 8 + j;
      float x = 0.f;
      if (row < 20)       x = W3[p * 5120 + k * 20 + row];
      else if (row == 20) x = Wocc[p * 256 + k];
      v[j] = (__bf16)x;
    }
    *reinterpret_cast<bf16x8*>(&ws[442368 + p * 8192 + row * 256 + c * 8]) = v;
  }
}

// Hf [pt][256 d] (32 16B-chunks/row), XOR swizzle chunk^=(pt&7): b64 writes
// 4 accesses/bank, b128 reads 8/bank (both at throughput minimum).
__global__ __launch_bounds__(256, 2) void tpose_main(
    const float* __restrict__ tpts, const float* __restrict__ bigpts,
    const float* __restrict__ viewdir, const float* __restrict__ frame,
    const float* __restrict__ b2g, const float* __restrict__ b3g,
    const float* __restrict__ boccg, const int* __restrict__ tflag,
    const __bf16* __restrict__ ws, float* __restrict__ out) {
  const __bf16* __restrict__ W1t = ws;
  const __bf16* __restrict__ W2t = ws + 49152;
  const __bf16* __restrict__ W3t = ws + 442368;

  __shared__ __align__(16) __bf16 Xf[128 * 40];    // [pt][k' pad 40]  10 KB
  __shared__ __align__(16) __bf16 Hf[128 * 256];   // swizzled         64 KB

  const int tid = threadIdx.x;
  const int w = tid >> 6;
  const int lane = tid & 63;
  const int lq = lane >> 4;
  const int ln = lane & 15;
  const int e = ln & 7;           // swizzle key (row & 7 == ln & 7 at every use)
  const int n0 = blockIdx.x * 128;

  // one-time X init: frame octet, 1.0 at slot 17, zeros 18-31
  if (tid < 128) {
    bf16x8 f8;
#pragma unroll
    for (int j = 0; j < 8; ++j) f8[j] = (__bf16)frame[j];
    *reinterpret_cast<bf16x8*>(&Xf[tid * 40]) = f8;
    bf16x8 z = {};
    z[1] = (__bf16)1.0f;  // slot 17 = constant-1 (bias feature)
    *reinterpret_cast<bf16x8*>(&Xf[tid * 40 + 16]) = z;
    bf16x8 z2 = {};
    *reinterpret_cast<bf16x8*>(&Xf[tid * 40 + 24]) = z2;
  }

  const int role = tid & 3;  // 0: tpts, 1: bigpts, 2: viewdir, 3: idle
  const float* __restrict__ dynsrc =
      (role == 0) ? tpts : (role == 1) ? bigpts : viewdir;

  // prefetch state for part 0
  float pre[2][3];
  float flv[2];
#pragma unroll
  for (int pass = 0; pass < 2; ++pass) {
    const int pt = (tid >> 2) + pass * 64;
    const int base3 = (n0 + pt) * 18;  // p=0
#pragma unroll
    for (int i = 0; i < 3; ++i) pre[pass][i] = dynsrc[base3 + i];
  }
#pragma unroll
  for (int s = 0; s < 2; ++s)
    flv[s] = (tflag[(n0 + w * 32 + s * 16 + ln) * 6] != 0) ? 1.f : 0.f;

  float psum0[2][4] = {{0.f, 0.f, 0.f, 0.f}, {0.f, 0.f, 0.f, 0.f}};
  float psum1[2][4] = {{0.f, 0.f, 0.f, 0.f}, {0.f, 0.f, 0.f, 0.f}};

  for (int p = 0; p < 6; ++p) {
    // ---- Phase A: store prefetched features (pure LDS) ----
    if (role < 3) {
#pragma unroll
      for (int pass = 0; pass < 2; ++pass) {
        const int pt = (tid >> 2) + pass * 64;
#pragma unroll
        for (int i = 0; i < 3; ++i)
          Xf[pt * 40 + 8 + role * 3 + i] = (__bf16)pre[pass][i];
      }
    }

    // prefetch part p+1 (latency hidden behind phases B-D)
    const int pn = (p < 5) ? p + 1 : 5;
    float fln[2];
#pragma unroll
    for (int pass = 0; pass < 2; ++pass) {
      const int pt = (tid >> 2) + pass * 64;
      const int base3 = ((n0 + pt) * 6 + pn) * 3;
#pragma unroll
      for (int i = 0; i < 3; ++i) pre[pass][i] = dynsrc[base3 + i];
    }
#pragma unroll
    for (int s = 0; s < 2; ++s)
      fln[s] = (tflag[(n0 + w * 32 + s * 16 + ln) * 6 + pn] != 0) ? 1.f : 0.f;

    // hoist phase-B weight loads above the barrier (global, LDS-independent:
    // L2 latency overlaps phase A + barrier drain)
    bf16x8 aw[4];
#pragma unroll
    for (int mt = 0; mt < 4; ++mt)
      aw[mt] = *reinterpret_cast<const bf16x8*>(
          &W1t[p * 8192 + (w * 64 + mt * 16 + ln) * 32 + lq * 8]);

    __syncthreads();  // (1) X visible; prev part's phase-D Hf reads done

    // ---- Phase B: H1 = relu(W1^T X) (bias inside GEMM via slot 17) ----
    f32x4 acc[4][8];
#pragma unroll
    for (int mt = 0; mt < 4; ++mt)
#pragma unroll
      for (int nt = 0; nt < 8; ++nt) acc[mt][nt] = f32x4{0.f, 0.f, 0.f, 0.f};
#pragma unroll
    for (int nt = 0; nt < 8; ++nt) {
      const bf16x8 xb =
          *reinterpret_cast<const bf16x8*>(&Xf[(nt * 16 + ln) * 40 + lq * 8]);
#pragma unroll
      for (int mt = 0; mt < 4; ++mt) acc[mt][nt] = MFMA16(aw[mt], xb, acc[mt][nt]);
    }
#pragma unroll
    for (int mt = 0; mt < 4; ++mt) {
      const int c = w * 8 + mt * 2 + (lq >> 1);
      const int off = ((c ^ e) << 3) + (lq & 1) * 4;
#pragma unroll
      for (int nt = 0; nt < 8; ++nt) {
        bf16x4v hv;
#pragma unroll
        for (int r = 0; r < 4; ++r) hv[r] = (__bf16)fmaxf(acc[mt][nt][r], 0.f);
        *reinterpret_cast<bf16x4v*>(&Hf[(nt * 16 + ln) * 256 + off]) = hv;
      }
    }

    __syncthreads();  // (2) H1 visible

    // ---- Phase C: H2 = relu(W2^T H1 + b2); b2 pre-init into acc ----
    {
      f32x4 b2v[4];
#pragma unroll
      for (int mt = 0; mt < 4; ++mt)
        b2v[mt] = *reinterpret_cast<const f32x4*>(
            &b2g[p * 256 + w * 64 + mt * 16 + lq * 4]);
#pragma unroll
      for (int mt = 0; mt < 4; ++mt)
#pragma unroll
        for (int nt = 0; nt < 8; ++nt) acc[mt][nt] = b2v[mt];  // bias preload
    }
    const __bf16* __restrict__ w2p = W2t + p * 65536 + (w * 64 + ln) * 256 + lq * 8;
    {
      bf16x8 a2[4];
#pragma unroll
      for (int mt = 0; mt < 4; ++mt)
        a2[mt] = *reinterpret_cast<const bf16x8*>(w2p + mt * 4096);
#pragma unroll
      for (int kk = 0; kk < 8; ++kk) {
        bf16x8 a2n[4];
        if (kk < 7) {
#pragma unroll
          for (int mt = 0; mt < 4; ++mt)
            a2n[mt] = *reinterpret_cast<const bf16x8*>(
                w2p + mt * 4096 + (kk + 1) * 32);
        }
#pragma unroll
        for (int nt = 0; nt < 8; ++nt) {
          const bf16x8 hb = *reinterpret_cast<const bf16x8*>(
              &Hf[(nt * 16 + ln) * 256 + (((kk * 4 + lq) ^ e) << 3)]);
#pragma unroll
          for (int mt = 0; mt < 4; ++mt) acc[mt][nt] = MFMA16(a2[mt], hb, acc[mt][nt]);
        }
#pragma unroll
        for (int mt = 0; mt < 4; ++mt) a2[mt] = a2n[mt];
      }
    }

    __syncthreads();  // (3) H1 reads done before overwrite

#pragma unroll
    for (int mt = 0; mt < 4; ++mt) {
      const int c = w * 8 + mt * 2 + (lq >> 1);
      const int off = ((c ^ e) << 3) + (lq & 1) * 4;
#pragma unroll
      for (int nt = 0; nt < 8; ++nt) {
        bf16x4v hv;
#pragma unroll
        for (int r = 0; r < 4; ++r) hv[r] = (__bf16)fmaxf(acc[mt][nt][r], 0.f);
        *reinterpret_cast<bf16x4v*>(&Hf[(nt * 16 + ln) * 256 + off]) = hv;
      }
    }

    __syncthreads();  // (4) H2 visible

    // ---- Phase D: raw||occ = W3^T H2 + b3; wave w -> pts [32w, 32w+32) ----
    f32x4 acc3[2][2];
    {
      float b3v[2][4];
#pragma unroll
      for (int mt = 0; mt < 2; ++mt)
#pragma unroll
        for (int r = 0; r < 4; ++r) {
          const int d = mt * 16 + lq * 4 + r;
          float v = 0.f;
          if (d < 20)       v = b3g[p * 20 + d];
          else if (d == 20) v = boccg[p];
          b3v[mt][r] = v;
        }
#pragma unroll
      for (int mt = 0; mt < 2; ++mt)
#pragma unroll
        for (int s = 0; s < 2; ++s)
#pragma unroll
          for (int r = 0; r < 4; ++r) acc3[mt][s][r] = b3v[mt][r];  // bias preload
    }
    const __bf16* __restrict__ w3p = W3t + p * 8192 + ln * 256 + lq * 8;
#pragma unroll
    for (int kk = 0; kk < 8; ++kk) {
      bf16x8 a3[2];
#pragma unroll
      for (int mt = 0; mt < 2; ++mt)
        a3[mt] = *reinterpret_cast<const bf16x8*>(w3p + mt * 4096 + kk * 32);
#pragma unroll
      for (int s = 0; s < 2; ++s) {
        const bf16x8 hb = *reinterpret_cast<const bf16x8*>(
            &Hf[(w * 32 + s * 16 + ln) * 256 + (((kk * 4 + lq) ^ e) << 3)]);
#pragma unroll
        for (int mt = 0; mt < 2; ++mt) acc3[mt][s] = MFMA16(a3[mt], hb, acc3[mt][s]);
      }
    }

    // Epilogue (bias already in acc3)
#pragma unroll
    for (int s = 0; s < 2; ++s) {
      const int pt = n0 + w * 32 + s * 16 + ln;
#pragma unroll
      for (int r = 0; r < 4; ++r) psum0[s][r] += flv[s] * acc3[0][s][r];
      if (lq == 0) {
#pragma unroll
        for (int r = 0; r < 4; ++r) psum1[s][r] += flv[s] * acc3[1][s][r];
      } else if (lq == 1) {  // dim 20 = occ (r=0)
        const float occ = 1.f / (1.f + __expf(-acc3[1][s][0]));
        out[pt * 27 + 21 + p] = flv[s] * occ;
        psum1[s][0] += flv[s] * occ;
      }
    }

    flv[0] = fln[0];
    flv[1] = fln[1];
  }  // p loop

  const float inv6 = 1.f / 6.f;
#pragma unroll
  for (int s = 0; s < 2; ++s) {
    const int pt = n0 + w * 32 + s * 16 + ln;
#pragma unroll
    for (int r = 0; r < 4; ++r) out[pt * 27 + lq * 4 + r] = psum0[s][r] * inv6;
    if (lq == 0) {
#pragma unroll
      for (int r = 0; r < 4; ++r) out[pt * 27 + 16 + r] = psum1[s][r] * inv6;
    } else if (lq == 1) {
      out[pt * 27 + 20] = psum1[s][0] * inv6;
    }
  }
}

extern "C" void kernel_launch(void* const* d_in, const int* in_sizes, int n_in,
                              void* d_out, int out_size, void* d_ws, size_t ws_size,
                              hipStream_t stream) {
  const float* tpts    = (const float*)d_in[0];
  const float* bigpts  = (const float*)d_in[1];
  const float* viewdir = (const float*)d_in[2];
  const float* frame   = (const float*)d_in[5];
  const float* W1      = (const float*)d_in[6];
  const float* b1      = (const float*)d_in[7];
  const float* W2      = (const float*)d_in[8];
  const float* b2      = (const float*)d_in[9];
  const float* W3      = (const float*)d_in[10];
  const float* b3      = (const float*)d_in[11];
  const float* Wocc    = (const float*)d_in[12];
  const float* bocc    = (const float*)d_in[13];
  const int*   tflag   = (const int*)d_in[14];
  __bf16* ws  = (__bf16*)d_ws;
  float*  out = (float*)d_out;

  prep_kernel<<<240, 256, 0, stream>>>(W1, b1, W2, W3, Wocc, ws);
  tpose_main<<<512, 256, 0, stream>>>(tpts, bigpts, viewdir, frame, b2, b3,
                                      bocc, tflag, ws, out);
}